// Round 4
// baseline (249.300 us; speedup 1.0000x reference)
//
#include <hip/hip_runtime.h>

// BDToGEConverter: out[b,s,p,d] = sum_k W[p,d,k] * x[b,s,k], W fixed & sparse.
// Per row (1280 outputs) only 84 nonzero. One wave per row: coalesced loads
// of just the needed lines, shfl-xor butterfly for the 4 dots, shfl
// broadcasts for the taps, 5 coalesced 16B stores per lane.
//
// Session evidence so far:
//   R1: in_sizes[0] is element count (clamp no-op, dur 208.3).
//   R3: nt stores null (207.8) — weak probe though: nt changes cache
//       retention, not DRAM bytes, for a full-line write-once stream.
//   Hard bounds: kernel < ~104 us (never in top-5); poison fill ~107 us;
//   write roofline says kernel should be ~28-30 us. ~70 us unattributed.
//
// R4 = CALIBRATION PROBE (deliberately slower): add a known ~512-dep-FMA
// VALU delay per wave, kept live via asm (rule #17), output unchanged.
//   outcome 1: kernel row enters top-5 (>110us) -> kernel was ~100us
//              (model A); next round attacks it with its own counters.
//   outcome 2: kernel hidden, dur +25..55us -> kernel ~30us at write
//              roofline; 208us floor is harness-owned -> ROOFLINE.
//   outcome 3: dur unchanged -> kernel not on the timed critical path
//              at all -> ROOFLINE.

#define BD_DIM 512
#define ROW_F4 320            // 8*160 floats / 4
#define N_ROWS_LOGICAL 32768  // B*S = 8*4096, fixed by the problem spec
#define DELAY_ITERS 512       // ~2048 cyc dependent-FMA chain per wave

typedef float vfloat4 __attribute__((ext_vector_type(4)));

__global__ __launch_bounds__(256) void bd2ge_kernel(
    const float* __restrict__ x, float* __restrict__ out, int n_rows)
{
    const int wave = threadIdx.x >> 6;
    const int lane = threadIdx.x & 63;
    const int row  = blockIdx.x * 4 + wave;
    if (row >= n_rows) return;

    const float* __restrict__ xr = x + (size_t)row * BD_DIM;

    // Opcode taps live in x[10..19] (cache line 0 of the row).
    float xa = 0.f;
    if (lane < 20) xa = xr[lane];
    // Nibble blocks x[64..127] (lines 2,3) — fully used.
    const float xb = xr[64 + lane];

    // Dots: t = (lane&15)*xb, butterfly-sum within each 16-lane group.
    float t = (float)(lane & 15) * xb;
    t += __shfl_xor(t, 1);
    t += __shfl_xor(t, 2);
    t += __shfl_xor(t, 4);
    t += __shfl_xor(t, 8);
    const float dA0 = __shfl(t, 0);   // ALU_LO      -> p=0, d=0
    const float dA1 = __shfl(t, 16);  // ALU_HI      -> p=1, d=0
    const float dB0 = __shfl(t, 32);  // AX_CARRY_LO -> p=0, d=1
    const float dB1 = __shfl(t, 48);  // AX_CARRY_HI -> p=1, d=1

    // Opcode taps broadcast (d = OP_START + ge_op).
    const float o25 = __shfl(xa, 16);
    const float o26 = __shfl(xa, 17);
    const float o27 = __shfl(xa, 10);
    const float o28 = __shfl(xa, 11);
    const float o29 = __shfl(xa, 12);
    const float o30 = __shfl(xa, 13);
    const float o31 = __shfl(xa, 14);
    const float o32 = __shfl(xa, 15);
    const float o33 = __shfl(xa, 18);
    const float o34 = __shfl(xa, 19);

    // --- CALIBRATION DELAY: known VALU work, not DCE-able, output-neutral.
    {
        float acc = xb + 1.0f;
        #pragma unroll 1
        for (int it = 0; it < DELAY_ITERS; ++it)
            acc = __builtin_fmaf(acc, 1.000000119f, 1.0f);
        asm volatile("" :: "v"(acc));   // keep the chain live (rule #17)
    }

    vfloat4* __restrict__ orow = (vfloat4*)(out + (size_t)row * (ROW_F4 * 4));

    #pragma unroll
    for (int j = 0; j < 5; ++j) {
        const int f = lane + j * 64;       // float4 index in [0,320)
        const int p = f / 40;              // position (40 float4 per p)
        const int q = f - p * 40;          // d = 4q..4q+3
        vfloat4 v;
        v.x = (q == 0) ? (p == 0 ? dA0 : (p == 1 ? dA1 : 0.f))
                       : (q == 7 ? o28 : (q == 8 ? o32 : 0.f));
        v.y = (q == 0) ? (p == 0 ? dB0 : (p == 1 ? dB1 : 0.f))
                       : (q == 6 ? o25 : (q == 7 ? o29 : (q == 8 ? o33 : 0.f)));
        v.z = (q == 6) ? o26 : (q == 7 ? o30 : (q == 8 ? o34 : 0.f));
        v.w = (q == 6) ? o27 : (q == 7 ? o31 : 0.f);
        __builtin_nontemporal_store(v, &orow[f]);   // unchanged from R3
    }
}

extern "C" void kernel_launch(void* const* d_in, const int* in_sizes, int n_in,
                              void* d_out, int out_size, void* d_ws, size_t ws_size,
                              hipStream_t stream)
{
    const float* x = (const float*)d_in[0];     // [B,S,512] fp32
    // d_in[1] = W_proj: fixed sparse tensor, fully hardcoded above — never read.
    float* out = (float*)d_out;                 // [B,S,8,160] fp32

    int n_rows = in_sizes[0] / BD_DIM;          // element count (R1)
    if (n_rows > N_ROWS_LOGICAL) n_rows = N_ROWS_LOGICAL;

    const int blocks = (n_rows + 3) / 4;        // 4 rows (waves) per 256-thread block
    bd2ge_kernel<<<blocks, 256, 0, stream>>>(x, out, n_rows);
}

// Round 5
// 211.943 us; speedup vs baseline: 1.1763x; 1.1763x over previous
//
#include <hip/hip_runtime.h>

// BDToGEConverter: out[b,s,p,d] = sum_k W[p,d,k] * x[b,s,k], W fixed & sparse.
// Per row (1280 outputs) only 84 nonzero. Wave-per-row structure with
// shfl-xor butterfly dots + shfl tap broadcasts + 5 coalesced 16B stores.
//
// Session evidence:
//   R1: in_sizes[0] is element count (clamp no-op).
//   R3: nt stores null (~207.8).
//   R4 calibration (+512 dep-FMA/wave): dur +41.5us, kernel STILL absent
//       from top-5 (<104.8us). => kernel is ON the timed path; base <63us;
//       model "kernel~100us" refuted. Pass-through magnitude (41.5us vs
//       ~13.6us throughput-bound estimate) says wave-overlap is poor ->
//       kernel likely LATENCY-bound (~45-63us): per-wave critical path is
//       HBM load (~900cy) + dependent 4-step shfl butterfly (~120cy each,
//       ds_bpermute) + 14 broadcast shfls, with tiny work per wave.
//
// R5: 4 rows per wave (ILP attack, bytes unchanged):
//   - 8 global loads issued up front (4 rows' xa+xb in flight at once)
//   - 4 independent butterfly chains interleaved -> hides shfl latency
//   - 20 nt dwordx4 stores. Grid 8192 -> 2048 blocks.
// Predict: dur 249 -> ~175-195 if latency-bound; ~207 if at write roofline
// (then ROOFLINE: 167.8MB writes + 12.6MB reads ~= 29us @6.3TB/s, floor
// owned by harness fill ~107us + restores).

#define BD_DIM 512
#define ROW_F4 320            // 8*160 floats / 4
#define N_ROWS_LOGICAL 32768  // B*S = 8*4096, fixed by the problem spec
#define RPW 4                 // rows per wave

typedef float vfloat4 __attribute__((ext_vector_type(4)));

__global__ __launch_bounds__(256) void bd2ge_kernel(
    const float* __restrict__ x, float* __restrict__ out, int n_rows)
{
    const int wave = threadIdx.x >> 6;
    const int lane = threadIdx.x & 63;
    const int r0   = (blockIdx.x * 4 + wave) * RPW;   // first of 4 rows
    if (r0 >= n_rows) return;

    // ---- issue all loads up front: 8 independent global loads in flight.
    float xa[RPW], xb[RPW];
    #pragma unroll
    for (int i = 0; i < RPW; ++i) {
        const float* __restrict__ xr = x + (size_t)(r0 + i) * BD_DIM;
        const bool ok = (r0 + i) < n_rows;
        // taps x[10..19] live in row line 0; guard to lanes<20 to avoid
        // fetching unused lines. xb: nibble blocks x[64..127], fully used.
        xa[i] = (ok && lane < 20) ? xr[lane] : 0.f;
        xb[i] = ok ? xr[64 + lane] : 0.f;
    }

    // ---- 4 independent butterfly chains, interleaved (hides ds_bpermute
    // latency ~120cy 4-deep instead of serializing one dependent chain).
    float t[RPW];
    #pragma unroll
    for (int i = 0; i < RPW; ++i)
        t[i] = (float)(lane & 15) * xb[i];
    #pragma unroll
    for (int s = 1; s <= 8; s <<= 1) {
        #pragma unroll
        for (int i = 0; i < RPW; ++i)
            t[i] += __shfl_xor(t[i], s);
    }

    float dA0[RPW], dA1[RPW], dB0[RPW], dB1[RPW];
    float o25[RPW], o26[RPW], o27[RPW], o28[RPW], o29[RPW];
    float o30[RPW], o31[RPW], o32[RPW], o33[RPW], o34[RPW];
    #pragma unroll
    for (int i = 0; i < RPW; ++i) {
        dA0[i] = __shfl(t[i], 0);    // ALU_LO      -> p=0, d=0
        dA1[i] = __shfl(t[i], 16);   // ALU_HI      -> p=1, d=0
        dB0[i] = __shfl(t[i], 32);   // AX_CARRY_LO -> p=0, d=1
        dB1[i] = __shfl(t[i], 48);   // AX_CARRY_HI -> p=1, d=1
        o25[i] = __shfl(xa[i], 16);
        o26[i] = __shfl(xa[i], 17);
        o27[i] = __shfl(xa[i], 10);
        o28[i] = __shfl(xa[i], 11);
        o29[i] = __shfl(xa[i], 12);
        o30[i] = __shfl(xa[i], 13);
        o31[i] = __shfl(xa[i], 14);
        o32[i] = __shfl(xa[i], 15);
        o33[i] = __shfl(xa[i], 18);
        o34[i] = __shfl(xa[i], 19);
    }

    // ---- 20 coalesced nt dwordx4 stores (4 rows x 5 per lane).
    #pragma unroll
    for (int j = 0; j < 5; ++j) {
        const int f = lane + j * 64;       // float4 index in [0,320)
        const int p = f / 40;              // position (40 float4 per p)
        const int q = f - p * 40;          // d = 4q..4q+3
        #pragma unroll
        for (int i = 0; i < RPW; ++i) {
            if ((r0 + i) >= n_rows) break;
            vfloat4* __restrict__ orow =
                (vfloat4*)(out + (size_t)(r0 + i) * (ROW_F4 * 4));
            vfloat4 v;
            v.x = (q == 0) ? (p == 0 ? dA0[i] : (p == 1 ? dA1[i] : 0.f))
                           : (q == 7 ? o28[i] : (q == 8 ? o32[i] : 0.f));
            v.y = (q == 0) ? (p == 0 ? dB0[i] : (p == 1 ? dB1[i] : 0.f))
                           : (q == 6 ? o25[i] : (q == 7 ? o29[i]
                                              : (q == 8 ? o33[i] : 0.f)));
            v.z = (q == 6) ? o26[i] : (q == 7 ? o30[i] : (q == 8 ? o34[i] : 0.f));
            v.w = (q == 6) ? o27[i] : (q == 7 ? o31[i] : 0.f);
            __builtin_nontemporal_store(v, &orow[f]);
        }
    }
}

extern "C" void kernel_launch(void* const* d_in, const int* in_sizes, int n_in,
                              void* d_out, int out_size, void* d_ws, size_t ws_size,
                              hipStream_t stream)
{
    const float* x = (const float*)d_in[0];     // [B,S,512] fp32
    // d_in[1] = W_proj: fixed sparse tensor, fully hardcoded above — never read.
    float* out = (float*)d_out;                 // [B,S,8,160] fp32

    int n_rows = in_sizes[0] / BD_DIM;          // element count (R1)
    if (n_rows > N_ROWS_LOGICAL) n_rows = N_ROWS_LOGICAL;

    // 4 waves/block * 4 rows/wave = 16 rows per 256-thread block.
    const int blocks = (n_rows + 16 - 1) / 16;
    bd2ge_kernel<<<blocks, 256, 0, stream>>>(x, out, n_rows);
}

// Round 6
// 207.320 us; speedup vs baseline: 1.2025x; 1.0223x over previous
//
#include <hip/hip_runtime.h>

// BDToGEConverter: out[b,s,p,d] = sum_k W[p,d,k] * x[b,s,k], W fixed & sparse.
// Per row (1280 outputs) only 84 nonzero:
//   p=0: d0 = sum k*x[64+k],  d1 = sum k*x[96+k]      (k=0..15)
//   p=1: d0 = sum k*x[80+k],  d1 = sum k*x[112+k]
//   all p, d=25..34: {x16,x17,x10,x11,x12,x13,x14,x15,x18,x19}
// One wave per row: coalesced loads of just the needed lines, shfl-xor
// butterfly for the 4 dots, shfl broadcasts for the taps, 5 coalesced
// 16B nt stores per lane (1 KB/wave/store, full-line, no RMW).
//
// SESSION CONCLUSION (R0-R5 ledger):
//   R1 clamp null        -> in_sizes[0] is element count.
//   R3 nt-store null     -> no L2 write-allocate pathology.
//   R4 +41.5us calibration delay passes through 1:1, delayed kernel still
//      absent from top-5 (<104.8us) -> kernel timed, base < 63us.
//   R5 4-row ILP null    -> kernel is NOT latency-bound.
//   => kernel is at its write roofline: 167.8 MB mandatory dense output
//      + 12.6 MB reads ~= 29us @ 6.3 TB/s (the rate the harness's own
//      poison fill sustains on this buffer). dur_us floor ~208 = harness
//      poison fill (~107us) + restores, invariant across all variants.
// This file reverts to the best-measured variant (R3, 207.8us).

#define BD_DIM 512
#define ROW_F4 320            // 8*160 floats / 4
#define N_ROWS_LOGICAL 32768  // B*S = 8*4096, fixed by the problem spec

typedef float vfloat4 __attribute__((ext_vector_type(4)));  // nt-store legal

__global__ __launch_bounds__(256) void bd2ge_kernel(
    const float* __restrict__ x, float* __restrict__ out, int n_rows)
{
    const int wave = threadIdx.x >> 6;
    const int lane = threadIdx.x & 63;
    const int row  = blockIdx.x * 4 + wave;
    if (row >= n_rows) return;

    const float* __restrict__ xr = x + (size_t)row * BD_DIM;

    // Opcode taps live in x[10..19] (cache line 0 of the row). Guard the load
    // to lanes <20 so line 1 (x[32..63], unused) is never fetched.
    float xa = 0.f;
    if (lane < 20) xa = xr[lane];
    // Nibble blocks x[64..127] (lines 2,3) — fully used.
    const float xb = xr[64 + lane];

    // Dots: t = (lane&15)*xb, butterfly-sum within each 16-lane group.
    float t = (float)(lane & 15) * xb;
    t += __shfl_xor(t, 1);
    t += __shfl_xor(t, 2);
    t += __shfl_xor(t, 4);
    t += __shfl_xor(t, 8);
    const float dA0 = __shfl(t, 0);   // ALU_LO      -> p=0, d=0
    const float dA1 = __shfl(t, 16);  // ALU_HI      -> p=1, d=0
    const float dB0 = __shfl(t, 32);  // AX_CARRY_LO -> p=0, d=1
    const float dB1 = __shfl(t, 48);  // AX_CARRY_HI -> p=1, d=1

    // Opcode taps broadcast (d = OP_START + ge_op).
    const float o25 = __shfl(xa, 16);
    const float o26 = __shfl(xa, 17);
    const float o27 = __shfl(xa, 10);
    const float o28 = __shfl(xa, 11);
    const float o29 = __shfl(xa, 12);
    const float o30 = __shfl(xa, 13);
    const float o31 = __shfl(xa, 14);
    const float o32 = __shfl(xa, 15);
    const float o33 = __shfl(xa, 18);
    const float o34 = __shfl(xa, 19);

    vfloat4* __restrict__ orow = (vfloat4*)(out + (size_t)row * (ROW_F4 * 4));

    #pragma unroll
    for (int j = 0; j < 5; ++j) {
        const int f = lane + j * 64;       // float4 index in [0,320)
        const int p = f / 40;              // position (40 float4 per p)
        const int q = f - p * 40;          // d = 4q..4q+3
        vfloat4 v;
        v.x = (q == 0) ? (p == 0 ? dA0 : (p == 1 ? dA1 : 0.f))
                       : (q == 7 ? o28 : (q == 8 ? o32 : 0.f));
        v.y = (q == 0) ? (p == 0 ? dB0 : (p == 1 ? dB1 : 0.f))
                       : (q == 6 ? o25 : (q == 7 ? o29 : (q == 8 ? o33 : 0.f)));
        v.z = (q == 6) ? o26 : (q == 7 ? o30 : (q == 8 ? o34 : 0.f));
        v.w = (q == 6) ? o27 : (q == 7 ? o31 : 0.f);
        // Write-once stream, never re-read: nontemporal hint.
        __builtin_nontemporal_store(v, &orow[f]);
    }
}

extern "C" void kernel_launch(void* const* d_in, const int* in_sizes, int n_in,
                              void* d_out, int out_size, void* d_ws, size_t ws_size,
                              hipStream_t stream)
{
    const float* x = (const float*)d_in[0];     // [B,S,512] fp32
    // d_in[1] = W_proj: fixed sparse tensor, fully hardcoded above — never read.
    float* out = (float*)d_out;                 // [B,S,8,160] fp32

    // in_sizes[0] is an element count (R1); clamp is correct either way.
    int n_rows = in_sizes[0] / BD_DIM;
    if (n_rows > N_ROWS_LOGICAL) n_rows = N_ROWS_LOGICAL;

    const int blocks = (n_rows + 3) / 4;        // 4 rows (waves) per 256-thread block
    bd2ge_kernel<<<blocks, 256, 0, stream>>>(x, out, n_rows);
}